// Round 5
// baseline (275.214 us; speedup 1.0000x reference)
//
#include <hip/hip_runtime.h>

// BlockinnerAttention: b=1, h=8, T_q=2048, T=4096, dk=64, BS=64, top-2 blocks/query.
// Round 5: round-4 structure (bucket by (head,block), SSPLIT=4 sub-WGs/bucket for
// occupancy) with the graph-capture bug fixed: hipMemsetAsync inside kernel_launch
// was not replayed by the captured graph -> poisoned hist -> scatter OOB writes ->
// persistent device corruption. Fix: zero_hist KERNEL (capture-safe) + defensive
// clamp of scatter positions so nothing can ever escape d_ws.
// Pipeline: zero -> hist -> scan(1 WG) -> scatter -> bucket -> combine.

#define NH      8
#define TQ      2048
#define TKV     4096
#define DK      64
#define BSZ     64
#define NB      (TKV / BSZ)     // 64 blocks per head
#define NQ_TOT  (NH * TQ)       // 16384
#define NENT    (NQ_TOT * 2)    // 32768
#define NBUCKET (NH * NB)       // 512
#define SSPLIT  4               // sub-WGs per bucket

// ws layout (bytes):
//   [0,      2048)   hist    (512 int)
//   [2048,   4100)   offsets (513 int)
//   [4160,   6208)   cursor  (512 int)
//   [8192, 139264)   list    (32768 int)
//   [139264, +8.9MB) partials: 32768 entries x 68 floats (o[64], m, l, pad)
#define WS_OFFSETS_B 2048
#define WS_CURSOR_B  4160
#define WS_LIST_B    8192
#define WS_PART_B    139264
#define WS_NEEDED    (WS_PART_B + (size_t)NENT * 68 * 4)

__global__ __launch_bounds__(256) void zero_hist_kernel(int* __restrict__ hist)
{
    const int t = blockIdx.x * 256 + threadIdx.x;
    if (t < NBUCKET) hist[t] = 0;
}

__global__ __launch_bounds__(256) void hist_kernel(
    const int* __restrict__ top2, int* __restrict__ hist)
{
    const int e = blockIdx.x * 256 + threadIdx.x;   // 0..NENT-1
    const int qi = e >> 1;
    const int blk = top2[e] & (NB - 1);             // defensive mask
    atomicAdd(hist + (((qi >> 11) << 6) | blk), 1);
}

__global__ __launch_bounds__(NBUCKET) void scan_kernel(
    const int* __restrict__ hist, int* __restrict__ offsets, int* __restrict__ cursor)
{
    __shared__ int sh[NBUCKET];
    const int t = threadIdx.x;
    sh[t] = hist[t];
    __syncthreads();
    for (int d = 1; d < NBUCKET; d <<= 1) {
        int vv = sh[t];
        int add = (t >= d) ? sh[t - d] : 0;
        __syncthreads();
        sh[t] = vv + add;
        __syncthreads();
    }
    const int excl = (t == 0) ? 0 : sh[t - 1];
    offsets[t] = excl;
    cursor[t] = excl;
    if (t == NBUCKET - 1) offsets[NBUCKET] = sh[t];
}

__global__ __launch_bounds__(256) void scatter_kernel(
    const int* __restrict__ top2, int* __restrict__ cursor, int* __restrict__ list)
{
    const int e = blockIdx.x * 256 + threadIdx.x;
    const int qi = e >> 1;
    const int blk = top2[e] & (NB - 1);
    int pos = atomicAdd(cursor + (((qi >> 11) << 6) | blk), 1);
    // Defensive clamp: even with corrupted counters, never write outside list[].
    pos = (pos < 0) ? 0 : (pos >= NENT ? NENT - 1 : pos);
    list[pos] = e;
}

__global__ __launch_bounds__(256, 4) void bucket_kernel(
    const float* __restrict__ q,
    const float* __restrict__ k,
    const float* __restrict__ v,
    const int*   __restrict__ offsets,
    const int*   __restrict__ list,
    float*       __restrict__ partials)
{
    const int bucket  = blockIdx.x & (NBUCKET - 1);  // sub-WGs 512 apart -> same XCD
    const int subtile = blockIdx.x >> 9;             // 0..3
    const int h    = bucket >> 6;
    const int blk  = bucket & (NB - 1);
    const int wave = threadIdx.x >> 6;
    const int lane = threadIdx.x & 63;
    const int g    = lane >> 4;     // row-in-chunk 0..3
    const int dc   = lane & 15;     // dim chunk 0..15

    const int start = offsets[bucket];
    const int nq    = offsets[bucket + 1] - start;
    const int first = subtile * 4 + wave;           // this wave's first entry
    if (first >= nq) return;

    // K/V block resident in registers: kreg[i] = K[4i+g][4dc..4dc+3]
    const size_t base = ((size_t)h * TKV + (size_t)blk * BSZ) * DK + g * DK + dc * 4;
    float4 kreg[16], vreg[16];
#pragma unroll
    for (int i = 0; i < 16; ++i) kreg[i] = *(const float4*)(k + base + i * 256);
#pragma unroll
    for (int i = 0; i < 16; ++i) vreg[i] = *(const float4*)(v + base + i * 256);

    for (int it = first; it < nq; it += 4 * SSPLIT) {
        const int e  = list[start + it];
        const int qi = e >> 1;
        const float4 qf = *(const float4*)(q + (size_t)qi * DK + dc * 4);

        // scores for rows 4i+g (group-reduced over dc)
        float sc[16];
#pragma unroll
        for (int i = 0; i < 16; ++i) {
            const float4 a = kreg[i];
            float p = a.x * qf.x + a.y * qf.y + a.z * qf.z + a.w * qf.w;
            p += __shfl_xor(p, 1);
            p += __shfl_xor(p, 2);
            p += __shfl_xor(p, 4);
            p += __shfl_xor(p, 8);
            sc[i] = p * 0.125f;     // 1/sqrt(64)
        }

        // block-local softmax partial (m, l) over all 64 rows
        float m = sc[0];
#pragma unroll
        for (int i = 1; i < 16; ++i) m = fmaxf(m, sc[i]);
        m = fmaxf(m, __shfl_xor(m, 16));
        m = fmaxf(m, __shfl_xor(m, 32));

        float l = 0.f;
#pragma unroll
        for (int i = 0; i < 16; ++i) { sc[i] = __expf(sc[i] - m); l += sc[i]; }
        l += __shfl_xor(l, 16);
        l += __shfl_xor(l, 32);

        // unnormalized o = sum_j w_j * V[j][:]
        float4 acc = make_float4(0.f, 0.f, 0.f, 0.f);
#pragma unroll
        for (int i = 0; i < 16; ++i) {
            const float w = sc[i];
            acc.x += vreg[i].x * w; acc.y += vreg[i].y * w;
            acc.z += vreg[i].z * w; acc.w += vreg[i].w * w;
        }
        acc.x += __shfl_xor(acc.x, 16); acc.y += __shfl_xor(acc.y, 16);
        acc.z += __shfl_xor(acc.z, 16); acc.w += __shfl_xor(acc.w, 16);
        acc.x += __shfl_xor(acc.x, 32); acc.y += __shfl_xor(acc.y, 32);
        acc.z += __shfl_xor(acc.z, 32); acc.w += __shfl_xor(acc.w, 32);

        float* p = partials + (size_t)e * 68;
        if (g == 0) *(float4*)(p + dc * 4) = acc;
        if (lane == 0) { p[64] = m; p[65] = l; }
    }
}

__global__ __launch_bounds__(256) void combine_kernel(
    const float* __restrict__ partials, float* __restrict__ out)
{
    const int t  = blockIdx.x * 256 + threadIdx.x;  // NQ_TOT*16 threads
    const int qi = t >> 4;
    const int dc = t & 15;
    const float* p0 = partials + (size_t)(qi * 2) * 68;
    const float* p1 = p0 + 68;
    const float m0 = p0[64], l0 = p0[65];
    const float m1 = p1[64], l1 = p1[65];
    const float m  = fmaxf(m0, m1);
    const float a0 = __expf(m0 - m), a1 = __expf(m1 - m);
    const float inv = 1.0f / (a0 * l0 + a1 * l1);
    const float4 o0 = *(const float4*)(p0 + dc * 4);
    const float4 o1 = *(const float4*)(p1 + dc * 4);
    float4 o;
    o.x = (o0.x * a0 + o1.x * a1) * inv;
    o.y = (o0.y * a0 + o1.y * a1) * inv;
    o.z = (o0.z * a0 + o1.z * a1) * inv;
    o.w = (o0.w * a0 + o1.w * a1) * inv;
    *(float4*)(out + (size_t)qi * DK + dc * 4) = o;
}

// ---------------- fallback (round-2 kernel, ws-free) ----------------
__global__ __launch_bounds__(256) void blockattn_fallback(
    const float* __restrict__ q, const float* __restrict__ k,
    const float* __restrict__ v, const int* __restrict__ top2,
    float* __restrict__ out)
{
    const int wave = threadIdx.x >> 6;
    const int lane = threadIdx.x & 63;
    const int qidx = (blockIdx.x << 2) + wave;
    const int bh   = qidx >> 11;
    const int g    = lane >> 4;
    const int dc   = lane & 15;

    const int2 idx = *(const int2*)(top2 + (size_t)qidx * 2);
    const size_t bh_off = (size_t)bh * (TKV * DK);
    const int off = g * DK + dc * 4;

    const float* kb0 = k + bh_off + (size_t)idx.x * (BSZ * DK) + off;
    const float* kb1 = k + bh_off + (size_t)idx.y * (BSZ * DK) + off;
    const float* vb0 = v + bh_off + (size_t)idx.x * (BSZ * DK) + off;
    const float* vb1 = v + bh_off + (size_t)idx.y * (BSZ * DK) + off;
    const float4 qf = *(const float4*)(q + (size_t)qidx * DK + dc * 4);

    float sc[32];
#pragma unroll
    for (int i = 0; i < 16; ++i) {
        const float4 a = *(const float4*)(kb0 + i * 256);
        float p = a.x*qf.x + a.y*qf.y + a.z*qf.z + a.w*qf.w;
        p += __shfl_xor(p,1); p += __shfl_xor(p,2); p += __shfl_xor(p,4); p += __shfl_xor(p,8);
        sc[i] = p * 0.125f;
    }
#pragma unroll
    for (int i = 0; i < 16; ++i) {
        const float4 a = *(const float4*)(kb1 + i * 256);
        float p = a.x*qf.x + a.y*qf.y + a.z*qf.z + a.w*qf.w;
        p += __shfl_xor(p,1); p += __shfl_xor(p,2); p += __shfl_xor(p,4); p += __shfl_xor(p,8);
        sc[16+i] = p * 0.125f;
    }
    float m = sc[0];
#pragma unroll
    for (int i = 1; i < 32; ++i) m = fmaxf(m, sc[i]);
    m = fmaxf(m, __shfl_xor(m,16)); m = fmaxf(m, __shfl_xor(m,32));
    float sum = 0.f;
#pragma unroll
    for (int i = 0; i < 32; ++i) { sc[i] = __expf(sc[i]-m); sum += sc[i]; }
    sum += __shfl_xor(sum,16); sum += __shfl_xor(sum,32);
    const float inv = 1.0f / sum;

    float4 acc = make_float4(0.f,0.f,0.f,0.f);
#pragma unroll
    for (int i = 0; i < 16; ++i) {
        const float4 a = *(const float4*)(vb0 + i * 256);
        acc.x += a.x*sc[i]; acc.y += a.y*sc[i]; acc.z += a.z*sc[i]; acc.w += a.w*sc[i];
    }
#pragma unroll
    for (int i = 0; i < 16; ++i) {
        const float4 a = *(const float4*)(vb1 + i * 256);
        acc.x += a.x*sc[16+i]; acc.y += a.y*sc[16+i]; acc.z += a.z*sc[16+i]; acc.w += a.w*sc[16+i];
    }
    acc.x += __shfl_xor(acc.x,16); acc.y += __shfl_xor(acc.y,16);
    acc.z += __shfl_xor(acc.z,16); acc.w += __shfl_xor(acc.w,16);
    acc.x += __shfl_xor(acc.x,32); acc.y += __shfl_xor(acc.y,32);
    acc.z += __shfl_xor(acc.z,32); acc.w += __shfl_xor(acc.w,32);

    if (g == 0) {
        float4 o;
        o.x = acc.x*inv; o.y = acc.y*inv; o.z = acc.z*inv; o.w = acc.w*inv;
        *(float4*)(out + (size_t)qidx * DK + dc * 4) = o;
    }
}

extern "C" void kernel_launch(void* const* d_in, const int* in_sizes, int n_in,
                              void* d_out, int out_size, void* d_ws, size_t ws_size,
                              hipStream_t stream) {
    const float* q    = (const float*)d_in[0];
    const float* k    = (const float*)d_in[1];
    const float* v    = (const float*)d_in[2];
    // d_in[3] is the scalar BS (=64), baked into kernel constants.
    const int*   top2 = (const int*)d_in[4];
    float*       out  = (float*)d_out;

    if (ws_size < WS_NEEDED) {
        dim3 grid(NQ_TOT / 4), block(256);
        hipLaunchKernelGGL(blockattn_fallback, grid, block, 0, stream, q, k, v, top2, out);
        return;
    }

    char* ws = (char*)d_ws;
    int* hist     = (int*)ws;
    int* offsets  = (int*)(ws + WS_OFFSETS_B);
    int* cursor   = (int*)(ws + WS_CURSOR_B);
    int* list     = (int*)(ws + WS_LIST_B);
    float* parts  = (float*)(ws + WS_PART_B);

    hipLaunchKernelGGL(zero_hist_kernel, dim3(2),          dim3(256), 0, stream, hist);
    hipLaunchKernelGGL(hist_kernel,      dim3(NENT / 256), dim3(256), 0, stream, top2, hist);
    hipLaunchKernelGGL(scan_kernel,      dim3(1),          dim3(NBUCKET), 0, stream, hist, offsets, cursor);
    hipLaunchKernelGGL(scatter_kernel,   dim3(NENT / 256), dim3(256), 0, stream, top2, cursor, list);
    hipLaunchKernelGGL(bucket_kernel,    dim3(NBUCKET * SSPLIT), dim3(256), 0, stream, q, k, v, offsets, list, parts);
    hipLaunchKernelGGL(combine_kernel,   dim3(NQ_TOT * 16 / 256), dim3(256), 0, stream, parts, out);
}

// Round 6
// 103.846 us; speedup vs baseline: 2.6502x; 2.6502x over previous
//
#include <hip/hip_runtime.h>

// BlockinnerAttention: b=1, h=8, T_q=2048, T=4096, dk=64, BS=64, top-2 blocks/query.
// Round 6: MFMA flash-bucket. Bucket queries by (head,block) (pipeline from r5),
// bucket kernel rewritten around mfma_f32_16x16x32_bf16:
//   - per wave: K/Vt B-fragments loaded ONCE from global (fp32->bf16), 64 VGPRs
//   - per 16-query tile: S = (Q*0.125)K^T (8 mfma), register softmax
//     (2 shfls/entry), P -> per-wave LDS slice -> A-frags, O = P V^T (8 mfma)
//   - partials (unnorm o, m, l) per entry; combine merges the 2 per query.
// Layouts (guide-verified): C/D col=lane&15,row=(lane>>4)*4+reg [m89/m91];
// A[m=lane&15][k=(lane>>4)*8+j] [m120]; B[n=lane&15][k=(lane>>4)*8+j] (gemm_bt).

#define NH      8
#define TQ      2048
#define TKV     4096
#define DK      64
#define BSZ     64
#define NB      (TKV / BSZ)     // 64 blocks per head
#define NQ_TOT  (NH * TQ)       // 16384
#define NENT    (NQ_TOT * 2)    // 32768
#define NBUCKET (NH * NB)       // 512
#define SSPLIT  2               // sub-WGs per bucket -> 8 worker waves/bucket

#define WS_OFFSETS_B 2048
#define WS_CURSOR_B  4160
#define WS_LIST_B    8192
#define WS_PART_B    139264
#define WS_NEEDED    (WS_PART_B + (size_t)NENT * 68 * 4)

typedef __attribute__((ext_vector_type(8))) short bf16x8;
typedef __attribute__((ext_vector_type(4))) float f32x4;

__device__ __forceinline__ short f2bf(float x) {
    union { float f; unsigned u; } c; c.f = x;
    unsigned r = c.u + 0x7fffu + ((c.u >> 16) & 1u);   // RNE
    return (short)(r >> 16);
}

__device__ __forceinline__ bf16x8 pack_bf16x8(float4 a, float4 b) {
    bf16x8 r;
    r[0] = f2bf(a.x); r[1] = f2bf(a.y); r[2] = f2bf(a.z); r[3] = f2bf(a.w);
    r[4] = f2bf(b.x); r[5] = f2bf(b.y); r[6] = f2bf(b.z); r[7] = f2bf(b.w);
    return r;
}

__global__ __launch_bounds__(256) void zero_hist_kernel(int* __restrict__ hist)
{
    const int t = blockIdx.x * 256 + threadIdx.x;
    if (t < NBUCKET) hist[t] = 0;
}

__global__ __launch_bounds__(256) void hist_kernel(
    const int* __restrict__ top2, int* __restrict__ hist)
{
    const int e = blockIdx.x * 256 + threadIdx.x;
    const int qi = e >> 1;
    const int blk = top2[e] & (NB - 1);
    atomicAdd(hist + (((qi >> 11) << 6) | blk), 1);
}

__global__ __launch_bounds__(NBUCKET) void scan_kernel(
    const int* __restrict__ hist, int* __restrict__ offsets, int* __restrict__ cursor)
{
    __shared__ int sh[NBUCKET];
    const int t = threadIdx.x;
    sh[t] = hist[t];
    __syncthreads();
    for (int d = 1; d < NBUCKET; d <<= 1) {
        int vv = sh[t];
        int add = (t >= d) ? sh[t - d] : 0;
        __syncthreads();
        sh[t] = vv + add;
        __syncthreads();
    }
    const int excl = (t == 0) ? 0 : sh[t - 1];
    offsets[t] = excl;
    cursor[t] = excl;
    if (t == NBUCKET - 1) offsets[NBUCKET] = sh[t];
}

__global__ __launch_bounds__(256) void scatter_kernel(
    const int* __restrict__ top2, int* __restrict__ cursor, int* __restrict__ list)
{
    const int e = blockIdx.x * 256 + threadIdx.x;
    const int qi = e >> 1;
    const int blk = top2[e] & (NB - 1);
    int pos = atomicAdd(cursor + (((qi >> 11) << 6) | blk), 1);
    pos = (pos < 0) ? 0 : (pos >= NENT ? NENT - 1 : pos);
    list[pos] = e;
}

__global__ __launch_bounds__(256, 2) void bucket_kernel(
    const float* __restrict__ q,
    const float* __restrict__ k,
    const float* __restrict__ v,
    const int*   __restrict__ offsets,
    const int*   __restrict__ list,
    float*       __restrict__ partials)
{
    // per-wave P buffer: 16 rows x 72 bf16 (stride 144 B, 16B-aligned)
    __shared__ short P_lds[4][16 * 72];

    const int bucket  = blockIdx.x & (NBUCKET - 1);
    const int subtile = blockIdx.x >> 9;            // 0..SSPLIT-1
    const int wave = threadIdx.x >> 6;
    const int lane = threadIdx.x & 63;
    const int W    = subtile * 4 + wave;            // worker wave id 0..7

    const int start = offsets[bucket];
    const int nq    = offsets[bucket + 1] - start;
    const int ntiles = (nq + 15) >> 4;
    if (W >= ntiles) return;

    const int h    = bucket >> 6;
    const int blk  = bucket & (NB - 1);
    const int n16  = lane & 15;                     // n / m / col index
    const int quad = lane >> 4;                     // 0..3

    const float* kb = k + ((size_t)h * TKV + (size_t)blk * BSZ) * DK;
    const float* vb = v + ((size_t)h * TKV + (size_t)blk * BSZ) * DK;

    // ---- K B-frags: kf[kt][ks] = K[kt*16+n16][ks*32+quad*8 .. +7] ----
    bf16x8 kf[4][2];
#pragma unroll
    for (int kt = 0; kt < 4; ++kt)
#pragma unroll
        for (int ks = 0; ks < 2; ++ks) {
            const float* p = kb + (kt * 16 + n16) * DK + ks * 32 + quad * 8;
            kf[kt][ks] = pack_bf16x8(*(const float4*)p, *(const float4*)(p + 4));
        }

    // ---- V^T B-frags: vf[dt][ks][jj] = V[ks*32+quad*8+jj][dt*16+n16] ----
    bf16x8 vf[4][2];
#pragma unroll
    for (int dt = 0; dt < 4; ++dt)
#pragma unroll
        for (int ks = 0; ks < 2; ++ks) {
            bf16x8 t;
#pragma unroll
            for (int jj = 0; jj < 8; ++jj)
                t[jj] = f2bf(vb[(ks * 32 + quad * 8 + jj) * DK + dt * 16 + n16]);
            vf[dt][ks] = t;
        }

    short* pl = &P_lds[wave][0];

    for (int t = W; t < ntiles; t += 4 * SSPLIT) {
        const int tbase = start + t * 16;

        // ---- Q A-frag: row m=n16 of this tile (pad rows -> entry 0 of bucket)
        const int em_idx = (t * 16 + n16 < nq) ? (tbase + n16) : start;
        const int qi = list[em_idx] >> 1;
        bf16x8 qf[2];
#pragma unroll
        for (int ks = 0; ks < 2; ++ks) {
            const float* p = q + (size_t)qi * DK + ks * 32 + quad * 8;
            float4 lo = *(const float4*)p, hi = *(const float4*)(p + 4);
            lo.x *= 0.125f; lo.y *= 0.125f; lo.z *= 0.125f; lo.w *= 0.125f;
            hi.x *= 0.125f; hi.y *= 0.125f; hi.z *= 0.125f; hi.w *= 0.125f;
            qf[ks] = pack_bf16x8(lo, hi);
        }

        // ---- S = (Q/8) K^T : acc[kt] C-layout row=quad*4+r (q), col=n16 (key)
        f32x4 acc[4];
#pragma unroll
        for (int kt = 0; kt < 4; ++kt) {
            f32x4 a = {0.f, 0.f, 0.f, 0.f};
            a = __builtin_amdgcn_mfma_f32_16x16x32_bf16(qf[0], kf[kt][0], a, 0, 0, 0);
            a = __builtin_amdgcn_mfma_f32_16x16x32_bf16(qf[1], kf[kt][1], a, 0, 0, 0);
            acc[kt] = a;
        }

        // ---- softmax per row-slot r (rows quad*4+r): reduce over kt + lane&15
        float m4[4], l4[4], P[4][4];
#pragma unroll
        for (int r = 0; r < 4; ++r) {
            float mx = fmaxf(fmaxf(acc[0][r], acc[1][r]), fmaxf(acc[2][r], acc[3][r]));
            mx = fmaxf(mx, __shfl_xor(mx, 1));
            mx = fmaxf(mx, __shfl_xor(mx, 2));
            mx = fmaxf(mx, __shfl_xor(mx, 4));
            mx = fmaxf(mx, __shfl_xor(mx, 8));
            float s = 0.f;
#pragma unroll
            for (int kt = 0; kt < 4; ++kt) { P[kt][r] = __expf(acc[kt][r] - mx); s += P[kt][r]; }
            s += __shfl_xor(s, 1);
            s += __shfl_xor(s, 2);
            s += __shfl_xor(s, 4);
            s += __shfl_xor(s, 8);
            m4[r] = mx; l4[r] = s;
        }

        // ---- P -> LDS (bf16, C-layout write): row=quad*4+r, col=kt*16+n16
#pragma unroll
        for (int r = 0; r < 4; ++r)
#pragma unroll
            for (int kt = 0; kt < 4; ++kt)
                pl[(quad * 4 + r) * 72 + kt * 16 + n16] = f2bf(P[kt][r]);

        // ---- P A-frags: lane m=n16 reads k=ks*32+quad*8..+7 (16B aligned)
        bf16x8 pf[2];
#pragma unroll
        for (int ks = 0; ks < 2; ++ks)
            pf[ks] = *(const bf16x8*)&pl[n16 * 72 + ks * 32 + quad * 8];

        // ---- O = P V^T : oacc[dt] row=quad*4+r (q), col=n16 (dim)
        f32x4 oacc[4];
#pragma unroll
        for (int dt = 0; dt < 4; ++dt) {
            f32x4 a = {0.f, 0.f, 0.f, 0.f};
            a = __builtin_amdgcn_mfma_f32_16x16x32_bf16(pf[0], vf[dt][0], a, 0, 0, 0);
            a = __builtin_amdgcn_mfma_f32_16x16x32_bf16(pf[1], vf[dt][1], a, 0, 0, 0);
            oacc[dt] = a;
        }

        // ---- store partials (unnormalized o, m, l) for real rows
#pragma unroll
        for (int r = 0; r < 4; ++r) {
            const int row = t * 16 + quad * 4 + r;
            if (row < nq) {
                const int e = list[tbase + quad * 4 + r];
                float* pp = partials + (size_t)e * 68;
#pragma unroll
                for (int dt = 0; dt < 4; ++dt)
                    pp[dt * 16 + n16] = oacc[dt][r];
                if (n16 == 0) pp[64] = m4[r];
                if (n16 == 1) pp[65] = l4[r];
            }
        }
    }
}

__global__ __launch_bounds__(256) void combine_kernel(
    const float* __restrict__ partials, float* __restrict__ out)
{
    const int t  = blockIdx.x * 256 + threadIdx.x;  // NQ_TOT*16 threads
    const int qi = t >> 4;
    const int dc = t & 15;
    const float* p0 = partials + (size_t)(qi * 2) * 68;
    const float* p1 = p0 + 68;
    const float m0 = p0[64], l0 = p0[65];
    const float m1 = p1[64], l1 = p1[65];
    const float m  = fmaxf(m0, m1);
    const float a0 = __expf(m0 - m), a1 = __expf(m1 - m);
    const float inv = 1.0f / (a0 * l0 + a1 * l1);
    const float4 o0 = *(const float4*)(p0 + dc * 4);
    const float4 o1 = *(const float4*)(p1 + dc * 4);
    float4 o;
    o.x = (o0.x * a0 + o1.x * a1) * inv;
    o.y = (o0.y * a0 + o1.y * a1) * inv;
    o.z = (o0.z * a0 + o1.z * a1) * inv;
    o.w = (o0.w * a0 + o1.w * a1) * inv;
    *(float4*)(out + (size_t)qi * DK + dc * 4) = o;
}

// ---------------- fallback (round-2 kernel, ws-free) ----------------
__global__ __launch_bounds__(256) void blockattn_fallback(
    const float* __restrict__ q, const float* __restrict__ k,
    const float* __restrict__ v, const int* __restrict__ top2,
    float* __restrict__ out)
{
    const int wave = threadIdx.x >> 6;
    const int lane = threadIdx.x & 63;
    const int qidx = (blockIdx.x << 2) + wave;
    const int bh   = qidx >> 11;
    const int g    = lane >> 4;
    const int dc   = lane & 15;

    const int2 idx = *(const int2*)(top2 + (size_t)qidx * 2);
    const size_t bh_off = (size_t)bh * (TKV * DK);
    const int off = g * DK + dc * 4;

    const float* kb0 = k + bh_off + (size_t)idx.x * (BSZ * DK) + off;
    const float* kb1 = k + bh_off + (size_t)idx.y * (BSZ * DK) + off;
    const float* vb0 = v + bh_off + (size_t)idx.x * (BSZ * DK) + off;
    const float* vb1 = v + bh_off + (size_t)idx.y * (BSZ * DK) + off;
    const float4 qf = *(const float4*)(q + (size_t)qidx * DK + dc * 4);

    float sc[32];
#pragma unroll
    for (int i = 0; i < 16; ++i) {
        const float4 a = *(const float4*)(kb0 + i * 256);
        float p = a.x*qf.x + a.y*qf.y + a.z*qf.z + a.w*qf.w;
        p += __shfl_xor(p,1); p += __shfl_xor(p,2); p += __shfl_xor(p,4); p += __shfl_xor(p,8);
        sc[i] = p * 0.125f;
    }
#pragma unroll
    for (int i = 0; i < 16; ++i) {
        const float4 a = *(const float4*)(kb1 + i * 256);
        float p = a.x*qf.x + a.y*qf.y + a.z*qf.z + a.w*qf.w;
        p += __shfl_xor(p,1); p += __shfl_xor(p,2); p += __shfl_xor(p,4); p += __shfl_xor(p,8);
        sc[16+i] = p * 0.125f;
    }
    float m = sc[0];
#pragma unroll
    for (int i = 1; i < 32; ++i) m = fmaxf(m, sc[i]);
    m = fmaxf(m, __shfl_xor(m,16)); m = fmaxf(m, __shfl_xor(m,32));
    float sum = 0.f;
#pragma unroll
    for (int i = 0; i < 32; ++i) { sc[i] = __expf(sc[i]-m); sum += sc[i]; }
    sum += __shfl_xor(sum,16); sum += __shfl_xor(sum,32);
    const float inv = 1.0f / sum;

    float4 acc = make_float4(0.f,0.f,0.f,0.f);
#pragma unroll
    for (int i = 0; i < 16; ++i) {
        const float4 a = *(const float4*)(vb0 + i * 256);
        acc.x += a.x*sc[i]; acc.y += a.y*sc[i]; acc.z += a.z*sc[i]; acc.w += a.w*sc[i];
    }
#pragma unroll
    for (int i = 0; i < 16; ++i) {
        const float4 a = *(const float4*)(vb1 + i * 256);
        acc.x += a.x*sc[16+i]; acc.y += a.y*sc[16+i]; acc.z += a.z*sc[16+i]; acc.w += a.w*sc[16+i];
    }
    acc.x += __shfl_xor(acc.x,16); acc.y += __shfl_xor(acc.y,16);
    acc.z += __shfl_xor(acc.z,16); acc.w += __shfl_xor(acc.w,16);
    acc.x += __shfl_xor(acc.x,32); acc.y += __shfl_xor(acc.y,32);
    acc.z += __shfl_xor(acc.z,32); acc.w += __shfl_xor(acc.w,32);

    if (g == 0) {
        float4 o;
        o.x = acc.x*inv; o.y = acc.y*inv; o.z = acc.z*inv; o.w = acc.w*inv;
        *(float4*)(out + (size_t)qidx * DK + dc * 4) = o;
    }
}

extern "C" void kernel_launch(void* const* d_in, const int* in_sizes, int n_in,
                              void* d_out, int out_size, void* d_ws, size_t ws_size,
                              hipStream_t stream) {
    const float* q    = (const float*)d_in[0];
    const float* k    = (const float*)d_in[1];
    const float* v    = (const float*)d_in[2];
    // d_in[3] is the scalar BS (=64), baked into kernel constants.
    const int*   top2 = (const int*)d_in[4];
    float*       out  = (float*)d_out;

    if (ws_size < WS_NEEDED) {
        dim3 grid(NQ_TOT / 4), block(256);
        hipLaunchKernelGGL(blockattn_fallback, grid, block, 0, stream, q, k, v, top2, out);
        return;
    }

    char* ws = (char*)d_ws;
    int* hist     = (int*)ws;
    int* offsets  = (int*)(ws + WS_OFFSETS_B);
    int* cursor   = (int*)(ws + WS_CURSOR_B);
    int* list     = (int*)(ws + WS_LIST_B);
    float* parts  = (float*)(ws + WS_PART_B);

    hipLaunchKernelGGL(zero_hist_kernel, dim3(2),          dim3(256), 0, stream, hist);
    hipLaunchKernelGGL(hist_kernel,      dim3(NENT / 256), dim3(256), 0, stream, top2, hist);
    hipLaunchKernelGGL(scan_kernel,      dim3(1),          dim3(NBUCKET), 0, stream, hist, offsets, cursor);
    hipLaunchKernelGGL(scatter_kernel,   dim3(NENT / 256), dim3(256), 0, stream, top2, cursor, list);
    hipLaunchKernelGGL(bucket_kernel,    dim3(NBUCKET * SSPLIT), dim3(256), 0, stream, q, k, v, offsets, list, parts);
    hipLaunchKernelGGL(combine_kernel,   dim3(NQ_TOT * 16 / 256), dim3(256), 0, stream, parts, out);
}

// Round 7
// 94.344 us; speedup vs baseline: 2.9171x; 1.1007x over previous
//
#include <hip/hip_runtime.h>

// BlockinnerAttention: b=1, h=8, T_q=2048, T=4096, dk=64, BS=64, top-2 blocks/query.
// Round 7: round-6 MFMA flash-bucket, preprocessing collapsed 6->4 kernels via
// fixed-capacity buckets: list[512][CAP]; scatter atomicAdd's a per-bucket cursor
// (which doubles as the count) -> hist and single-WG scan kernels eliminated.
// CAP=256 vs Poisson(64) bucket sizes: overflow probability < 1e-80, clamped
// defensively so nothing can escape d_ws.
// Pipeline: zero(512 ints) -> scatter -> bucket (MFMA) -> combine.

#define NH      8
#define TQ      2048
#define TKV     4096
#define DK      64
#define BSZ     64
#define NB      (TKV / BSZ)     // 64 blocks per head
#define NQ_TOT  (NH * TQ)       // 16384
#define NENT    (NQ_TOT * 2)    // 32768
#define NBUCKET (NH * NB)       // 512
#define SSPLIT  2               // sub-WGs per bucket -> 8 worker waves/bucket
#define CAP     256             // fixed bucket capacity

// ws layout (bytes):
//   [0,     2048)      cursor (512 int) -- doubles as per-bucket count
//   [4096,  528384)    list   (512 * CAP int)
//   [528384, +8.9MB)   partials: 32768 entries x 68 floats (o[64], m, l, pad)
#define WS_LIST_B    4096
#define WS_PART_B    528384
#define WS_NEEDED    (WS_PART_B + (size_t)NENT * 68 * 4)

typedef __attribute__((ext_vector_type(8))) short bf16x8;
typedef __attribute__((ext_vector_type(4))) float f32x4;

__device__ __forceinline__ short f2bf(float x) {
    union { float f; unsigned u; } c; c.f = x;
    unsigned r = c.u + 0x7fffu + ((c.u >> 16) & 1u);   // RNE
    return (short)(r >> 16);
}

__device__ __forceinline__ bf16x8 pack_bf16x8(float4 a, float4 b) {
    bf16x8 r;
    r[0] = f2bf(a.x); r[1] = f2bf(a.y); r[2] = f2bf(a.z); r[3] = f2bf(a.w);
    r[4] = f2bf(b.x); r[5] = f2bf(b.y); r[6] = f2bf(b.z); r[7] = f2bf(b.w);
    return r;
}

__global__ __launch_bounds__(NBUCKET) void zero_cursor_kernel(int* __restrict__ cursor)
{
    cursor[threadIdx.x] = 0;
}

__global__ __launch_bounds__(256) void scatter_kernel(
    const int* __restrict__ top2, int* __restrict__ cursor, int* __restrict__ list)
{
    const int e = blockIdx.x * 256 + threadIdx.x;   // 0..NENT-1
    const int qi = e >> 1;
    const int blk = top2[e] & (NB - 1);             // defensive mask
    const int b = ((qi >> 11) << 6) | blk;          // bucket = head*64 + blk
    int pos = atomicAdd(cursor + b, 1);
    pos = (pos < 0) ? 0 : (pos >= CAP ? CAP - 1 : pos);  // clamp: never escape ws
    list[b * CAP + pos] = e;
}

__global__ __launch_bounds__(256, 2) void bucket_kernel(
    const float* __restrict__ q,
    const float* __restrict__ k,
    const float* __restrict__ v,
    const int*   __restrict__ cursor,
    const int*   __restrict__ list,
    float*       __restrict__ partials)
{
    // per-wave P buffer: 16 rows x 72 bf16 (stride 144 B, 16B-aligned)
    __shared__ short P_lds[4][16 * 72];

    const int bucket  = blockIdx.x & (NBUCKET - 1);
    const int subtile = blockIdx.x >> 9;            // 0..SSPLIT-1
    const int wave = threadIdx.x >> 6;
    const int lane = threadIdx.x & 63;
    const int W    = subtile * 4 + wave;            // worker wave id 0..7

    const int start = bucket * CAP;
    int nq = cursor[bucket];
    nq = (nq > CAP) ? CAP : nq;
    const int ntiles = (nq + 15) >> 4;
    if (W >= ntiles) return;

    const int h    = bucket >> 6;
    const int blk  = bucket & (NB - 1);
    const int n16  = lane & 15;                     // n / m / col index
    const int quad = lane >> 4;                     // 0..3

    const float* kb = k + ((size_t)h * TKV + (size_t)blk * BSZ) * DK;
    const float* vb = v + ((size_t)h * TKV + (size_t)blk * BSZ) * DK;

    // ---- K B-frags: kf[kt][ks] = K[kt*16+n16][ks*32+quad*8 .. +7] ----
    bf16x8 kf[4][2];
#pragma unroll
    for (int kt = 0; kt < 4; ++kt)
#pragma unroll
        for (int ks = 0; ks < 2; ++ks) {
            const float* p = kb + (kt * 16 + n16) * DK + ks * 32 + quad * 8;
            kf[kt][ks] = pack_bf16x8(*(const float4*)p, *(const float4*)(p + 4));
        }

    // ---- V^T B-frags: vf[dt][ks][jj] = V[ks*32+quad*8+jj][dt*16+n16] ----
    bf16x8 vf[4][2];
#pragma unroll
    for (int dt = 0; dt < 4; ++dt)
#pragma unroll
        for (int ks = 0; ks < 2; ++ks) {
            bf16x8 t;
#pragma unroll
            for (int jj = 0; jj < 8; ++jj)
                t[jj] = f2bf(vb[(ks * 32 + quad * 8 + jj) * DK + dt * 16 + n16]);
            vf[dt][ks] = t;
        }

    short* pl = &P_lds[wave][0];

    for (int t = W; t < ntiles; t += 4 * SSPLIT) {
        const int tbase = start + t * 16;

        // ---- Q A-frag: row m=n16 of this tile (pad rows -> entry 0 of bucket)
        const int em_idx = (t * 16 + n16 < nq) ? (tbase + n16) : start;
        const int qi = list[em_idx] >> 1;
        bf16x8 qf[2];
#pragma unroll
        for (int ks = 0; ks < 2; ++ks) {
            const float* p = q + (size_t)qi * DK + ks * 32 + quad * 8;
            float4 lo = *(const float4*)p, hi = *(const float4*)(p + 4);
            lo.x *= 0.125f; lo.y *= 0.125f; lo.z *= 0.125f; lo.w *= 0.125f;
            hi.x *= 0.125f; hi.y *= 0.125f; hi.z *= 0.125f; hi.w *= 0.125f;
            qf[ks] = pack_bf16x8(lo, hi);
        }

        // ---- S = (Q/8) K^T : acc[kt] C-layout row=quad*4+r (q), col=n16 (key)
        f32x4 acc[4];
#pragma unroll
        for (int kt = 0; kt < 4; ++kt) {
            f32x4 a = {0.f, 0.f, 0.f, 0.f};
            a = __builtin_amdgcn_mfma_f32_16x16x32_bf16(qf[0], kf[kt][0], a, 0, 0, 0);
            a = __builtin_amdgcn_mfma_f32_16x16x32_bf16(qf[1], kf[kt][1], a, 0, 0, 0);
            acc[kt] = a;
        }

        // ---- softmax per row-slot r (rows quad*4+r): reduce over kt + lane&15
        float m4[4], l4[4], P[4][4];
#pragma unroll
        for (int r = 0; r < 4; ++r) {
            float mx = fmaxf(fmaxf(acc[0][r], acc[1][r]), fmaxf(acc[2][r], acc[3][r]));
            mx = fmaxf(mx, __shfl_xor(mx, 1));
            mx = fmaxf(mx, __shfl_xor(mx, 2));
            mx = fmaxf(mx, __shfl_xor(mx, 4));
            mx = fmaxf(mx, __shfl_xor(mx, 8));
            float s = 0.f;
#pragma unroll
            for (int kt = 0; kt < 4; ++kt) { P[kt][r] = __expf(acc[kt][r] - mx); s += P[kt][r]; }
            s += __shfl_xor(s, 1);
            s += __shfl_xor(s, 2);
            s += __shfl_xor(s, 4);
            s += __shfl_xor(s, 8);
            m4[r] = mx; l4[r] = s;
        }

        // ---- P -> LDS (bf16, C-layout write): row=quad*4+r, col=kt*16+n16
#pragma unroll
        for (int r = 0; r < 4; ++r)
#pragma unroll
            for (int kt = 0; kt < 4; ++kt)
                pl[(quad * 4 + r) * 72 + kt * 16 + n16] = f2bf(P[kt][r]);

        // ---- P A-frags: lane m=n16 reads k=ks*32+quad*8..+7 (16B aligned)
        bf16x8 pf[2];
#pragma unroll
        for (int ks = 0; ks < 2; ++ks)
            pf[ks] = *(const bf16x8*)&pl[n16 * 72 + ks * 32 + quad * 8];

        // ---- O = P V^T : oacc[dt] row=quad*4+r (q), col=n16 (dim)
        f32x4 oacc[4];
#pragma unroll
        for (int dt = 0; dt < 4; ++dt) {
            f32x4 a = {0.f, 0.f, 0.f, 0.f};
            a = __builtin_amdgcn_mfma_f32_16x16x32_bf16(pf[0], vf[dt][0], a, 0, 0, 0);
            a = __builtin_amdgcn_mfma_f32_16x16x32_bf16(pf[1], vf[dt][1], a, 0, 0, 0);
            oacc[dt] = a;
        }

        // ---- store partials (unnormalized o, m, l) for real rows
#pragma unroll
        for (int r = 0; r < 4; ++r) {
            const int row = t * 16 + quad * 4 + r;
            if (row < nq) {
                const int e = list[tbase + quad * 4 + r];
                float* pp = partials + (size_t)e * 68;
#pragma unroll
                for (int dt = 0; dt < 4; ++dt)
                    pp[dt * 16 + n16] = oacc[dt][r];
                if (n16 == 0) pp[64] = m4[r];
                if (n16 == 1) pp[65] = l4[r];
            }
        }
    }
}

__global__ __launch_bounds__(256) void combine_kernel(
    const float* __restrict__ partials, float* __restrict__ out)
{
    const int t  = blockIdx.x * 256 + threadIdx.x;  // NQ_TOT*16 threads
    const int qi = t >> 4;
    const int dc = t & 15;
    const float* p0 = partials + (size_t)(qi * 2) * 68;
    const float* p1 = p0 + 68;
    const float m0 = p0[64], l0 = p0[65];
    const float m1 = p1[64], l1 = p1[65];
    const float m  = fmaxf(m0, m1);
    const float a0 = __expf(m0 - m), a1 = __expf(m1 - m);
    const float inv = 1.0f / (a0 * l0 + a1 * l1);
    const float4 o0 = *(const float4*)(p0 + dc * 4);
    const float4 o1 = *(const float4*)(p1 + dc * 4);
    float4 o;
    o.x = (o0.x * a0 + o1.x * a1) * inv;
    o.y = (o0.y * a0 + o1.y * a1) * inv;
    o.z = (o0.z * a0 + o1.z * a1) * inv;
    o.w = (o0.w * a0 + o1.w * a1) * inv;
    *(float4*)(out + (size_t)qi * DK + dc * 4) = o;
}

// ---------------- fallback (round-2 kernel, ws-free) ----------------
__global__ __launch_bounds__(256) void blockattn_fallback(
    const float* __restrict__ q, const float* __restrict__ k,
    const float* __restrict__ v, const int* __restrict__ top2,
    float* __restrict__ out)
{
    const int wave = threadIdx.x >> 6;
    const int lane = threadIdx.x & 63;
    const int qidx = (blockIdx.x << 2) + wave;
    const int bh   = qidx >> 11;
    const int g    = lane >> 4;
    const int dc   = lane & 15;

    const int2 idx = *(const int2*)(top2 + (size_t)qidx * 2);
    const size_t bh_off = (size_t)bh * (TKV * DK);
    const int off = g * DK + dc * 4;

    const float* kb0 = k + bh_off + (size_t)idx.x * (BSZ * DK) + off;
    const float* kb1 = k + bh_off + (size_t)idx.y * (BSZ * DK) + off;
    const float* vb0 = v + bh_off + (size_t)idx.x * (BSZ * DK) + off;
    const float* vb1 = v + bh_off + (size_t)idx.y * (BSZ * DK) + off;
    const float4 qf = *(const float4*)(q + (size_t)qidx * DK + dc * 4);

    float sc[32];
#pragma unroll
    for (int i = 0; i < 16; ++i) {
        const float4 a = *(const float4*)(kb0 + i * 256);
        float p = a.x*qf.x + a.y*qf.y + a.z*qf.z + a.w*qf.w;
        p += __shfl_xor(p,1); p += __shfl_xor(p,2); p += __shfl_xor(p,4); p += __shfl_xor(p,8);
        sc[i] = p * 0.125f;
    }
#pragma unroll
    for (int i = 0; i < 16; ++i) {
        const float4 a = *(const float4*)(kb1 + i * 256);
        float p = a.x*qf.x + a.y*qf.y + a.z*qf.z + a.w*qf.w;
        p += __shfl_xor(p,1); p += __shfl_xor(p,2); p += __shfl_xor(p,4); p += __shfl_xor(p,8);
        sc[16+i] = p * 0.125f;
    }
    float m = sc[0];
#pragma unroll
    for (int i = 1; i < 32; ++i) m = fmaxf(m, sc[i]);
    m = fmaxf(m, __shfl_xor(m,16)); m = fmaxf(m, __shfl_xor(m,32));
    float sum = 0.f;
#pragma unroll
    for (int i = 0; i < 32; ++i) { sc[i] = __expf(sc[i]-m); sum += sc[i]; }
    sum += __shfl_xor(sum,16); sum += __shfl_xor(sum,32);
    const float inv = 1.0f / sum;

    float4 acc = make_float4(0.f,0.f,0.f,0.f);
#pragma unroll
    for (int i = 0; i < 16; ++i) {
        const float4 a = *(const float4*)(vb0 + i * 256);
        acc.x += a.x*sc[i]; acc.y += a.y*sc[i]; acc.z += a.z*sc[i]; acc.w += a.w*sc[i];
    }
#pragma unroll
    for (int i = 0; i < 16; ++i) {
        const float4 a = *(const float4*)(vb1 + i * 256);
        acc.x += a.x*sc[16+i]; acc.y += a.y*sc[16+i]; acc.z += a.z*sc[16+i]; acc.w += a.w*sc[16+i];
    }
    acc.x += __shfl_xor(acc.x,16); acc.y += __shfl_xor(acc.y,16);
    acc.z += __shfl_xor(acc.z,16); acc.w += __shfl_xor(acc.w,16);
    acc.x += __shfl_xor(acc.x,32); acc.y += __shfl_xor(acc.y,32);
    acc.z += __shfl_xor(acc.z,32); acc.w += __shfl_xor(acc.w,32);

    if (g == 0) {
        float4 o;
        o.x = acc.x*inv; o.y = acc.y*inv; o.z = acc.z*inv; o.w = acc.w*inv;
        *(float4*)(out + (size_t)qidx * DK + dc * 4) = o;
    }
}

extern "C" void kernel_launch(void* const* d_in, const int* in_sizes, int n_in,
                              void* d_out, int out_size, void* d_ws, size_t ws_size,
                              hipStream_t stream) {
    const float* q    = (const float*)d_in[0];
    const float* k    = (const float*)d_in[1];
    const float* v    = (const float*)d_in[2];
    // d_in[3] is the scalar BS (=64), baked into kernel constants.
    const int*   top2 = (const int*)d_in[4];
    float*       out  = (float*)d_out;

    if (ws_size < WS_NEEDED) {
        dim3 grid(NQ_TOT / 4), block(256);
        hipLaunchKernelGGL(blockattn_fallback, grid, block, 0, stream, q, k, v, top2, out);
        return;
    }

    char* ws = (char*)d_ws;
    int* cursor  = (int*)ws;
    int* list    = (int*)(ws + WS_LIST_B);
    float* parts = (float*)(ws + WS_PART_B);

    hipLaunchKernelGGL(zero_cursor_kernel, dim3(1),          dim3(NBUCKET), 0, stream, cursor);
    hipLaunchKernelGGL(scatter_kernel,     dim3(NENT / 256), dim3(256), 0, stream, top2, cursor, list);
    hipLaunchKernelGGL(bucket_kernel,      dim3(NBUCKET * SSPLIT), dim3(256), 0, stream, q, k, v, cursor, list, parts);
    hipLaunchKernelGGL(combine_kernel,     dim3(NQ_TOT * 16 / 256), dim3(256), 0, stream, parts, out);
}